// Round 2
// baseline (695.790 us; speedup 1.0000x reference)
//
#include <hip/hip_runtime.h>

// SparseTransE scoring:
//   ent rows [0, n_ent) are L2-normalized (norm floored at EPS);
//   relation rows [n_ent, n_ent+n_rel) are used as-is.
//   score(h,r,t) = -sum((eh/||eh|| + er - et/||et||)^2)
//
// R2 (resubmit after broker timeout): two-pass MLP attack.
//   Pass A (inv_norm_kernel): streaming 513MB read computes inv-norm per entity
//     into d_ws (2MB). Pure-sequential => fill-like ~80% HBM BW.
//   Pass B (transe_score_lds_kernel): random 1KB h/t row gathers are staged
//     straight into LDS via global_load_lds (no VGPR destinations) -> in-flight
//     bytes bounded by LDS (32KB/block x 5 blocks/CU = 160KB/CU) instead of the
//     VGPR file (~48KB/CU in R1). Relation rows (1MB hot table, L2-resident)
//     stay as register loads. Norm butterflies are gone from the gather path;
//     only the final 4-value score butterfly remains. No __syncthreads at all:
//     each wave owns a private LDS region and waits only its own vmcnt.
//   Fallback: if ws_size < n_rows*4B, use the R1 fused kernel (verbatim).

#define EMB 256
#define EPS 1e-12f

// ---------------- Pass A: per-entity inverse norms (streaming) ----------------
#define NRM_RPW 4

__global__ __launch_bounds__(256) void inv_norm_kernel(
    const float* __restrict__ emb, float* __restrict__ inv_norm,
    const int* __restrict__ n_ent_ptr)
{
    const int wave = (blockIdx.x * blockDim.x + threadIdx.x) >> 6;
    const int lane = threadIdx.x & 63;
    const int n_ent = *n_ent_ptr;
    const int base = wave * NRM_RPW;
    if (base >= n_ent) return;

    float s[NRM_RPW];
#pragma unroll
    for (int i = 0; i < NRM_RPW; ++i) {
        const int row = base + i;
        float4 v = make_float4(0.f, 0.f, 0.f, 0.f);
        if (row < n_ent)
            v = ((const float4*)(emb + (size_t)row * EMB))[lane];
        s[i] = v.x * v.x + v.y * v.y + v.z * v.z + v.w * v.w;
    }
#pragma unroll
    for (int d = 32; d >= 1; d >>= 1)
#pragma unroll
        for (int i = 0; i < NRM_RPW; ++i)
            s[i] += __shfl_xor(s[i], d, 64);

    if (lane == 0) {
        const float4 o = make_float4(
            1.0f / fmaxf(sqrtf(s[0]), EPS),
            1.0f / fmaxf(sqrtf(s[1]), EPS),
            1.0f / fmaxf(sqrtf(s[2]), EPS),
            1.0f / fmaxf(sqrtf(s[3]), EPS));
        if (base + NRM_RPW <= n_ent) {
            *(float4*)(inv_norm + base) = o;
        } else {
            inv_norm[base] = o.x;
            if (base + 1 < n_ent) inv_norm[base + 1] = o.y;
            if (base + 2 < n_ent) inv_norm[base + 2] = o.z;
        }
    }
}

// ---------------- Pass B: LDS-staged gather + score ---------------------------
#define SPW 4
#define WPB 4   // waves per block (block = 256)

__global__ __launch_bounds__(256, 5) void transe_score_lds_kernel(
    const float* __restrict__ emb,
    const float* __restrict__ inv_norm,
    const int* __restrict__ pos_h, const int* __restrict__ pos_r, const int* __restrict__ pos_t,
    const int* __restrict__ neg_h, const int* __restrict__ neg_r, const int* __restrict__ neg_t,
    const int* __restrict__ n_ent_ptr,
    float* __restrict__ out, int B)
{
    // Per wave: 2*SPW entity rows of 1KB = 8KB; 32KB/block => 5 blocks/CU.
    __shared__ float lds[WPB * 2 * SPW * EMB];

    const int wave = (blockIdx.x * blockDim.x + threadIdx.x) >> 6;
    const int lane = threadIdx.x & 63;
    const int wib  = threadIdx.x >> 6;
    const int base = wave * SPW;
    if (base >= 2 * B) return;

    const int n_ent = *n_ent_ptr;

    const int* __restrict__ hsrc;
    const int* __restrict__ rsrc;
    const int* __restrict__ tsrc;
    int off;
    if (base < B) { hsrc = pos_h; rsrc = pos_r; tsrc = pos_t; off = base; }
    else          { hsrc = neg_h; rsrc = neg_r; tsrc = neg_t; off = base - B; }

    const int4 hh = *(const int4*)(hsrc + off);
    const int4 rr = *(const int4*)(rsrc + off);
    const int4 tt = *(const int4*)(tsrc + off);
    const int hi[SPW] = {hh.x, hh.y, hh.z, hh.w};
    const int ri[SPW] = {rr.x, rr.y, rr.z, rr.w};
    const int ti[SPW] = {tt.x, tt.y, tt.z, tt.w};

    // Entity rows -> private LDS region (no VGPR dests; deep MLP).
    float* wl = lds + wib * (2 * SPW * EMB);
#pragma unroll
    for (int s = 0; s < SPW; ++s) {
        const float* hg = emb + (size_t)hi[s] * EMB + lane * 4;
        const float* tg = emb + (size_t)ti[s] * EMB + lane * 4;
        __builtin_amdgcn_global_load_lds(hg, wl + s * EMB,         16, 0, 0);
        __builtin_amdgcn_global_load_lds(tg, wl + (SPW + s) * EMB, 16, 0, 0);
    }

    // Relation rows (hot, L2-resident) + inverse norms -> registers.
    float4 rv[SPW];
    float inh[SPW], itn[SPW];
#pragma unroll
    for (int s = 0; s < SPW; ++s) {
        rv[s]  = ((const float4*)(emb + ((size_t)ri[s] + (size_t)n_ent) * EMB))[lane];
        inh[s] = inv_norm[hi[s]];
        itn[s] = inv_norm[ti[s]];
    }

    // Wait for OUR wave's LDS-bound loads (vmcnt is per-wave; no barrier).
    asm volatile("s_waitcnt vmcnt(0)" ::: "memory");
    __builtin_amdgcn_sched_barrier(0);

    float sq[SPW];
#pragma unroll
    for (int s = 0; s < SPW; ++s) {
        const float4 hv = ((const float4*)(wl + s * EMB))[lane];
        const float4 tv = ((const float4*)(wl + (SPW + s) * EMB))[lane];
        const float vx = hv.x * inh[s] + rv[s].x - tv.x * itn[s];
        const float vy = hv.y * inh[s] + rv[s].y - tv.y * itn[s];
        const float vz = hv.z * inh[s] + rv[s].z - tv.z * itn[s];
        const float vw = hv.w * inh[s] + rv[s].w - tv.w * itn[s];
        sq[s] = vx * vx + vy * vy + vz * vz + vw * vw;
    }
#pragma unroll
    for (int d = 32; d >= 1; d >>= 1)
#pragma unroll
        for (int k = 0; k < SPW; ++k)
            sq[k] += __shfl_xor(sq[k], d, 64);

    if (lane == 0)
        *(float4*)(out + base) = make_float4(-sq[0], -sq[1], -sq[2], -sq[3]);
}

// ---------------- Fallback: R1 fused kernel (ws too small) --------------------
__global__ __launch_bounds__(256) void transe_score_fused_kernel(
    const float* __restrict__ emb,
    const int* __restrict__ pos_h, const int* __restrict__ pos_r, const int* __restrict__ pos_t,
    const int* __restrict__ neg_h, const int* __restrict__ neg_r, const int* __restrict__ neg_t,
    const int* __restrict__ n_ent_ptr,
    float* __restrict__ out, int B)
{
    const int wave = (blockIdx.x * blockDim.x + threadIdx.x) >> 6;
    const int lane = threadIdx.x & 63;
    const int base = wave * SPW;
    if (base >= 2 * B) return;

    const int n_ent = *n_ent_ptr;

    const int* __restrict__ hsrc;
    const int* __restrict__ rsrc;
    const int* __restrict__ tsrc;
    int off;
    if (base < B) { hsrc = pos_h; rsrc = pos_r; tsrc = pos_t; off = base; }
    else          { hsrc = neg_h; rsrc = neg_r; tsrc = neg_t; off = base - B; }

    const int4 hh = *(const int4*)(hsrc + off);
    const int4 rr = *(const int4*)(rsrc + off);
    const int4 tt = *(const int4*)(tsrc + off);

    const int hi[SPW] = {hh.x, hh.y, hh.z, hh.w};
    const int ri[SPW] = {rr.x, rr.y, rr.z, rr.w};
    const int ti[SPW] = {tt.x, tt.y, tt.z, tt.w};

    float4 hv[SPW], tv[SPW], rv[SPW];
#pragma unroll
    for (int s = 0; s < SPW; ++s) {
        hv[s] = ((const float4*)(emb + (size_t)hi[s] * EMB))[lane];
        tv[s] = ((const float4*)(emb + (size_t)ti[s] * EMB))[lane];
        rv[s] = ((const float4*)(emb + ((size_t)ri[s] + (size_t)n_ent) * EMB))[lane];
    }

    float red[2 * SPW];
#pragma unroll
    for (int s = 0; s < SPW; ++s) {
        red[s]       = hv[s].x * hv[s].x + hv[s].y * hv[s].y + hv[s].z * hv[s].z + hv[s].w * hv[s].w;
        red[SPW + s] = tv[s].x * tv[s].x + tv[s].y * tv[s].y + tv[s].z * tv[s].z + tv[s].w * tv[s].w;
    }
#pragma unroll
    for (int d = 32; d >= 1; d >>= 1) {
#pragma unroll
        for (int k = 0; k < 2 * SPW; ++k)
            red[k] += __shfl_xor(red[k], d, 64);
    }

    float sq[SPW];
#pragma unroll
    for (int s = 0; s < SPW; ++s) {
        const float inh = 1.0f / fmaxf(sqrtf(red[s]), EPS);
        const float itn = 1.0f / fmaxf(sqrtf(red[SPW + s]), EPS);
        const float vx = hv[s].x * inh + rv[s].x - tv[s].x * itn;
        const float vy = hv[s].y * inh + rv[s].y - tv[s].y * itn;
        const float vz = hv[s].z * inh + rv[s].z - tv[s].z * itn;
        const float vw = hv[s].w * inh + rv[s].w - tv[s].w * itn;
        sq[s] = vx * vx + vy * vy + vz * vz + vw * vw;
    }
#pragma unroll
    for (int d = 32; d >= 1; d >>= 1) {
#pragma unroll
        for (int k = 0; k < SPW; ++k)
            sq[k] += __shfl_xor(sq[k], d, 64);
    }

    if (lane == 0)
        *(float4*)(out + base) = make_float4(-sq[0], -sq[1], -sq[2], -sq[3]);
}

extern "C" void kernel_launch(void* const* d_in, const int* in_sizes, int n_in,
                              void* d_out, int out_size, void* d_ws, size_t ws_size,
                              hipStream_t stream) {
    const float* emb  = (const float*)d_in[0];
    const int* pos_h  = (const int*)d_in[1];
    const int* pos_r  = (const int*)d_in[2];
    const int* pos_t  = (const int*)d_in[3];
    const int* neg_h  = (const int*)d_in[4];
    const int* neg_r  = (const int*)d_in[5];
    const int* neg_t  = (const int*)d_in[6];
    const int* n_ent  = (const int*)d_in[7];
    float* out = (float*)d_out;

    const int B = in_sizes[1];                       // 65536
    const int total = 2 * B;                         // 131072 scores
    const size_t rows_total = (size_t)in_sizes[0] / EMB;  // n_ent + n_rel (upper bound on n_ent)

    const int waves_b = (total + SPW - 1) / SPW;
    const int grid_b  = (waves_b * 64 + 255) / 256;

    if (d_ws != nullptr && ws_size >= rows_total * sizeof(float)) {
        float* inv_norm = (float*)d_ws;

        const long long waves_a = ((long long)rows_total + NRM_RPW - 1) / NRM_RPW;
        const int grid_a = (int)((waves_a * 64 + 255) / 256);

        inv_norm_kernel<<<grid_a, 256, 0, stream>>>(emb, inv_norm, n_ent);
        transe_score_lds_kernel<<<grid_b, 256, 0, stream>>>(
            emb, inv_norm, pos_h, pos_r, pos_t, neg_h, neg_r, neg_t, n_ent, out, B);
    } else {
        transe_score_fused_kernel<<<grid_b, 256, 0, stream>>>(
            emb, pos_h, pos_r, pos_t, neg_h, neg_r, neg_t, n_ent, out, B);
    }
}

// Round 3
// 603.883 us; speedup vs baseline: 1.1522x; 1.1522x over previous
//
#include <hip/hip_runtime.h>

// SparseTransE scoring:
//   ent rows [0, n_ent) are L2-normalized (norm floored at EPS) on the fly;
//   relation rows [n_ent, n_ent+n_rel) are used as-is.
//   score(h,r,t) = -sum((eh/||eh|| + er - et/||et||)^2)
//
// R3 = revert to R1 (best proven: 602.5/605.6 us).
// R2's two-pass variant (streaming inv-norm pre-pass + LDS-staged gather)
// regressed +90us and falsified both the critical-path and VGPR-MLP theories:
// removing the norm butterflies AND moving load destinations to LDS changed
// the gather kernel's time by ~0. The gather runs at the machine's random
// 1KB-row floor; the only remaining cost was Pass A's 513MB pre-read, removed
// here by reverting to the fused single kernel.
//
// Structure (R1): 4 scores per wave (SPW=4) — 12 independent 1KB row loads in
// flight per wave; one int4 broadcast per index table; interleaved butterfly
// reductions (8 values through 6 shfl stages); coalesced float4 store, lane 0.
// B=65536 is a multiple of SPW, so each wave's 4 scores are all-pos or all-neg
// (wave-uniform branch) and the out store is 16B-aligned.

#define EMB 256
#define EPS 1e-12f
#define SPW 4

__global__ __launch_bounds__(256) void transe_score_kernel(
    const float* __restrict__ emb,
    const int* __restrict__ pos_h, const int* __restrict__ pos_r, const int* __restrict__ pos_t,
    const int* __restrict__ neg_h, const int* __restrict__ neg_r, const int* __restrict__ neg_t,
    const int* __restrict__ n_ent_ptr,
    float* __restrict__ out, int B)
{
    const int wave = (blockIdx.x * blockDim.x + threadIdx.x) >> 6;
    const int lane = threadIdx.x & 63;
    const int base = wave * SPW;
    if (base >= 2 * B) return;

    const int n_ent = *n_ent_ptr;

    const int* __restrict__ hsrc;
    const int* __restrict__ rsrc;
    const int* __restrict__ tsrc;
    int off;
    if (base < B) { hsrc = pos_h; rsrc = pos_r; tsrc = pos_t; off = base; }
    else          { hsrc = neg_h; rsrc = neg_r; tsrc = neg_t; off = base - B; }

    const int4 hh = *(const int4*)(hsrc + off);
    const int4 rr = *(const int4*)(rsrc + off);
    const int4 tt = *(const int4*)(tsrc + off);

    const int hi[SPW] = {hh.x, hh.y, hh.z, hh.w};
    const int ri[SPW] = {rr.x, rr.y, rr.z, rr.w};
    const int ti[SPW] = {tt.x, tt.y, tt.z, tt.w};

    // Issue all 12 row loads before any use — compiler keeps them in flight.
    float4 hv[SPW], tv[SPW], rv[SPW];
#pragma unroll
    for (int s = 0; s < SPW; ++s) {
        hv[s] = ((const float4*)(emb + (size_t)hi[s] * EMB))[lane];
        tv[s] = ((const float4*)(emb + (size_t)ti[s] * EMB))[lane];
        rv[s] = ((const float4*)(emb + ((size_t)ri[s] + (size_t)n_ent) * EMB))[lane];
    }

    // Per-lane partial |h|^2, |t|^2 for all 4 scores, then one interleaved
    // 6-stage butterfly over 8 values (hides shfl latency with ILP).
    float red[2 * SPW];
#pragma unroll
    for (int s = 0; s < SPW; ++s) {
        red[s]       = hv[s].x * hv[s].x + hv[s].y * hv[s].y + hv[s].z * hv[s].z + hv[s].w * hv[s].w;
        red[SPW + s] = tv[s].x * tv[s].x + tv[s].y * tv[s].y + tv[s].z * tv[s].z + tv[s].w * tv[s].w;
    }
#pragma unroll
    for (int d = 32; d >= 1; d >>= 1) {
#pragma unroll
        for (int k = 0; k < 2 * SPW; ++k)
            red[k] += __shfl_xor(red[k], d, 64);
    }

    float sq[SPW];
#pragma unroll
    for (int s = 0; s < SPW; ++s) {
        const float inh = 1.0f / fmaxf(sqrtf(red[s]), EPS);
        const float itn = 1.0f / fmaxf(sqrtf(red[SPW + s]), EPS);
        const float vx = hv[s].x * inh + rv[s].x - tv[s].x * itn;
        const float vy = hv[s].y * inh + rv[s].y - tv[s].y * itn;
        const float vz = hv[s].z * inh + rv[s].z - tv[s].z * itn;
        const float vw = hv[s].w * inh + rv[s].w - tv[s].w * itn;
        sq[s] = vx * vx + vy * vy + vz * vz + vw * vw;
    }
#pragma unroll
    for (int d = 32; d >= 1; d >>= 1) {
#pragma unroll
        for (int k = 0; k < SPW; ++k)
            sq[k] += __shfl_xor(sq[k], d, 64);
    }

    if (lane == 0)
        *(float4*)(out + base) = make_float4(-sq[0], -sq[1], -sq[2], -sq[3]);
}

extern "C" void kernel_launch(void* const* d_in, const int* in_sizes, int n_in,
                              void* d_out, int out_size, void* d_ws, size_t ws_size,
                              hipStream_t stream) {
    const float* emb  = (const float*)d_in[0];
    const int* pos_h  = (const int*)d_in[1];
    const int* pos_r  = (const int*)d_in[2];
    const int* pos_t  = (const int*)d_in[3];
    const int* neg_h  = (const int*)d_in[4];
    const int* neg_r  = (const int*)d_in[5];
    const int* neg_t  = (const int*)d_in[6];
    const int* n_ent  = (const int*)d_in[7];
    float* out = (float*)d_out;

    const int B = in_sizes[1];               // 65536
    const int total = 2 * B;                 // 131072 scores
    const int waves = (total + SPW - 1) / SPW;
    const int block = 256;                   // 4 waves/block
    const int grid = (waves * 64 + block - 1) / block;

    transe_score_kernel<<<grid, block, 0, stream>>>(
        emb, pos_h, pos_r, pos_t, neg_h, neg_r, neg_t, n_ent, out, B);
}